// Round 19
// baseline (1773.611 us; speedup 1.0000x reference)
//
#include <hip/hip_runtime.h>
#include <cstdint>

typedef __bf16 bf16x8 __attribute__((ext_vector_type(8)));
typedef __bf16 bf16x4 __attribute__((ext_vector_type(4)));
typedef float  f32x4  __attribute__((ext_vector_type(4)));

#define VOCAB 32000
#define EMB   512
#define HID   1024
#define LAT   512
#define BATCH 32
#define TSTEP 127          // T-1
#define MROWS 4064         // TSTEP*BATCH
#define MPAD  4096
#define G4    4096         // 4*HID
#define NBLK2 64           // lstm worker blocks (512 thr each)
#define NTM   32           // logits M tiles
#define NTN   250          // logits N tiles
#define HWORDS 16384       // tagged u64 words per parity (BATCH*512)

__device__ __forceinline__ float sigf(float x){ return 1.0f / (1.0f + __expf(-x)); }
__device__ __forceinline__ float tanhfast(float x){
    float ax = fabsf(x);
    float e  = __expf(-2.0f * ax);
    float t  = (1.0f - e) / (1.0f + e);
    return copysignf(t, x);
}

// async global->LDS, 16B/lane; LDS base wave-uniform (HW adds lane*16)
__device__ __forceinline__ void gll16(void* lds, const void* gsrc){
    __builtin_amdgcn_global_load_lds(
        (const __attribute__((address_space(1))) unsigned int*)gsrc,
        (__attribute__((address_space(3))) unsigned int*)lds,
        16, 0, 0);
}
// raw workgroup barrier (execution sync only; no vmcnt drain)
__device__ __forceinline__ void bar(){ asm volatile("s_barrier" ::: "memory"); }

// ---------------------------------------------------------------------------
// K0 (grid 192): blocks 0..127: h0 = latent@W_lh^T + b_lh, written as TAGGED
// u64 (tag=0) into parity0 of hbt; poison parity1 tags; zero Hall pad rows.
// blocks 128..191: W_hh fp32->bf16.
// ---------------------------------------------------------------------------
__global__ __launch_bounds__(256) void init_kernel(
    const float* __restrict__ latent,
    const float* __restrict__ Wlh,
    const float* __restrict__ blh,
    unsigned long long* __restrict__ hbt,
    __bf16* __restrict__ Hall,
    const float* __restrict__ Whh,
    __bf16* __restrict__ Whhb)
{
    if (blockIdx.x >= 128){
        const int n4 = G4 * HID / 4;
        for (int i = (blockIdx.x - 128) * 256 + threadIdx.x; i < n4; i += 64 * 256){
            float4 v = ((const float4*)Whh)[i];
            bf16x4 o = { (__bf16)v.x, (__bf16)v.y, (__bf16)v.z, (__bf16)v.w };
            ((bf16x4*)Whhb)[i] = o;
        }
        return;
    }

    int id = blockIdx.x * 256 + threadIdx.x;   // 32768 = BATCH*HID
    int b = id >> 10, j = id & 1023;
    float s = blh[j];
    const float4* lr = (const float4*)(latent + (size_t)b * LAT);
    const float4* wr = (const float4*)(Wlh + (size_t)j * LAT);
    for (int k = 0; k < LAT / 4; ++k){
        float4 a = lr[k], w = wr[k];
        s += a.x * w.x + a.y * w.y + a.z * w.z + a.w * w.w;
    }
    // pack pairs: even lane takes neighbor's value (pairs are lanes 2k,2k+1)
    float s_hi = __shfl_down(s, 1);
    if ((j & 1) == 0){
        union { __bf16 h[2]; unsigned u; } pk;
        pk.h[0] = (__bf16)s; pk.h[1] = (__bf16)s_hi;
        hbt[(size_t)b * 512 + (j >> 1)] = (unsigned long long)pk.u;  // tag 0
    }
    if (id < HWORDS)                      // poison parity1 (replay safety)
        hbt[HWORDS + id] = 0xFFFFFFFF00000000ULL;
    Hall[(size_t)MROWS * HID + id] = (__bf16)0.0f;  // pad rows 4064..4095
}

// ---------------------------------------------------------------------------
// K1: xg[r][4096] = emb[tok(r)] @ W_ih^T + b_ih + b_hh   (fp32 in, fp32 out)
// ---------------------------------------------------------------------------
__global__ __launch_bounds__(256) void gemm_xg(
    const float* __restrict__ emb,
    const float* __restrict__ Wih,
    const int*   __restrict__ tok,
    float*       __restrict__ xg,
    const float* __restrict__ bih,
    const float* __restrict__ bhh)
{
    __shared__ __bf16 As[2][128 * 32];
    __shared__ __bf16 Bs[2][128 * 32];

    const int tid  = threadIdx.x;
    const int wid  = tid >> 6, lane = tid & 63;
    const int tile_n = blockIdx.x, tile_m = blockIdx.y;
    const int wr = wid >> 1, wc = wid & 1;

    f32x4 acc[4][4] = {};

    auto stage = [&](int kt, int buf){
        #pragma unroll
        for (int j = 0; j < 2; ++j){
            const int slot = tid + j * 256;
            const int row  = slot >> 2;
            const int kb   = kt * 32 + (slot & 3) * 8;
            {
                const int brow = tile_n * 128 + row;
                const float4* p = (const float4*)(Wih + (size_t)brow * EMB + kb);
                float4 u = p[0], v = p[1];
                bf16x8 w = { (__bf16)u.x, (__bf16)u.y, (__bf16)u.z, (__bf16)u.w,
                             (__bf16)v.x, (__bf16)v.y, (__bf16)v.z, (__bf16)v.w };
                *(bf16x8*)&Bs[buf][row * 32 + (slot & 3) * 8] = w;
            }
            {
                int r = tile_m * 128 + row;
                int rc = (r < MROWS) ? r : (MROWS - 1);
                int token = tok[(rc & 31) * 128 + (rc >> 5)];   // tokens[b][t]
                const float4* p = (const float4*)(emb + (size_t)token * EMB + kb);
                float4 u = p[0], v = p[1];
                bf16x8 w = { (__bf16)u.x, (__bf16)u.y, (__bf16)u.z, (__bf16)u.w,
                             (__bf16)v.x, (__bf16)v.y, (__bf16)v.z, (__bf16)v.w };
                *(bf16x8*)&As[buf][row * 32 + (slot & 3) * 8] = w;
            }
        }
    };

    const int KT = EMB / 32;
    stage(0, 0);
    for (int kt = 0; kt < KT; ++kt){
        const int buf = kt & 1;
        __syncthreads();
        if (kt + 1 < KT) stage(kt + 1, buf ^ 1);
        const __bf16* Abuf = As[buf];
        const __bf16* Bbuf = Bs[buf];
        const int ar = lane & 15, ko = (lane >> 4) * 8;
        bf16x8 av[4], bv[4];
        #pragma unroll
        for (int m = 0; m < 4; ++m)
            av[m] = *(const bf16x8*)&Abuf[(wr * 64 + m * 16 + ar) * 32 + ko];
        #pragma unroll
        for (int n = 0; n < 4; ++n)
            bv[n] = *(const bf16x8*)&Bbuf[(wc * 64 + n * 16 + ar) * 32 + ko];
        #pragma unroll
        for (int m = 0; m < 4; ++m)
            #pragma unroll
            for (int n = 0; n < 4; ++n)
                acc[m][n] = __builtin_amdgcn_mfma_f32_16x16x32_bf16(av[m], bv[n], acc[m][n], 0, 0, 0);
    }

    const int r0 = tile_m * 128 + wr * 64 + ((lane >> 4) << 2);
    const int c0 = tile_n * 128 + wc * 64 + (lane & 15);
    #pragma unroll
    for (int m = 0; m < 4; ++m){
        #pragma unroll
        for (int n = 0; n < 4; ++n){
            const int col = c0 + n * 16;
            float badd = bih[col] + bhh[col];
            #pragma unroll
            for (int q = 0; q < 4; ++q){
                int row = r0 + m * 16 + q;
                xg[(size_t)row * G4 + col] = acc[m][n][q] + badd;
            }
        }
    }
}

// ---------------------------------------------------------------------------
// K3: logits = Hall @ W_out^T + b_out, 128^2 tile, GROUP_M=8 + XCD swizzle.
// Swapped MFMA operands -> lane holds 4 consecutive output cols -> f32x4
// nontemporal C-stores.
// ---------------------------------------------------------------------------
template<int BF16B>
__global__ __launch_bounds__(256) void gemm_logits(
    const __bf16* __restrict__ A,     // Hall, padded to MPAD rows, K=HID
    const float*  __restrict__ Bf,    // W_out fp32 (BF16B=0)
    const __bf16* __restrict__ Bb,    // W_out bf16 (BF16B=1)
    float*        __restrict__ C,
    const float*  __restrict__ bias)
{
    __shared__ __bf16 As[2][128 * 32];
    __shared__ __bf16 Bs[2][128 * 32];

    const int tid  = threadIdx.x;
    const int wid  = tid >> 6, lane = tid & 63;
    const int bid = blockIdx.x;
    const int s   = (bid & 7) * (NTM * NTN / 8) + (bid >> 3);
    const int g   = s / (8 * NTN), rem = s % (8 * NTN);
    const int tile_m = g * 8 + (rem & 7);
    const int tile_n = rem >> 3;
    const int wr = wid >> 1, wc = wid & 1;

    f32x4 acc[4][4] = {};

    auto stage = [&](int kt, int buf){
        const int kb = kt * 32 + (lane & 3) * 8;
        #pragma unroll
        for (int c2 = 0; c2 < 2; ++c2){
            int rA = tile_m * 128 + c2 * 64 + wid * 16 + (lane >> 2);
            gll16(&As[buf][c2 * 2048 + wid * 512], A + (size_t)rA * HID + kb);
            if constexpr (BF16B){
                int rB = tile_n * 128 + c2 * 64 + wid * 16 + (lane >> 2);
                gll16(&Bs[buf][c2 * 2048 + wid * 512], Bb + (size_t)rB * HID + kb);
            }
        }
        if constexpr (!BF16B){
            #pragma unroll
            for (int j = 0; j < 2; ++j){
                const int slot = tid + j * 256;
                const int row  = slot >> 2;
                const int kb2  = kt * 32 + (slot & 3) * 8;
                const int brow = tile_n * 128 + row;
                const float4* p = (const float4*)(Bf + (size_t)brow * HID + kb2);
                float4 u = p[0], v = p[1];
                bf16x8 w = { (__bf16)u.x, (__bf16)u.y, (__bf16)u.z, (__bf16)u.w,
                             (__bf16)v.x, (__bf16)v.y, (__bf16)v.z, (__bf16)v.w };
                *(bf16x8*)&Bs[buf][row * 32 + (slot & 3) * 8] = w;
            }
        }
    };

    const int KT = HID / 32;
    stage(0, 0);
    for (int kt = 0; kt < KT; ++kt){
        const int buf = kt & 1;
        __syncthreads();                 // drains vmcnt (gll) + lgkmcnt
        if (kt + 1 < KT) stage(kt + 1, buf ^ 1);
        const __bf16* Abuf = As[buf];
        const __bf16* Bbuf = Bs[buf];
        const int ar = lane & 15, ko = (lane >> 4) * 8;
        bf16x8 av[4], bv[4];
        #pragma unroll
        for (int m = 0; m < 4; ++m)
            av[m] = *(const bf16x8*)&Abuf[(wr * 64 + m * 16 + ar) * 32 + ko];
        #pragma unroll
        for (int n = 0; n < 4; ++n)
            bv[n] = *(const bf16x8*)&Bbuf[(wc * 64 + n * 16 + ar) * 32 + ko];
        #pragma unroll
        for (int m = 0; m < 4; ++m)
            #pragma unroll
            for (int n = 0; n < 4; ++n)
                acc[m][n] = __builtin_amdgcn_mfma_f32_16x16x32_bf16(
                    bv[n], av[m], acc[m][n], 0, 0, 0);   // SWAPPED
    }

    const int r0 = tile_m * 128 + wr * 64 + (lane & 15);
    const int c0 = tile_n * 128 + wc * 64 + ((lane >> 4) << 2);
    #pragma unroll
    for (int m = 0; m < 4; ++m){
        const int row = r0 + m * 16;
        if (row < MROWS){
            const int t = row >> 5, b = row & 31;
            float* crow = &C[((size_t)b * TSTEP + t) * VOCAB];
            #pragma unroll
            for (int n = 0; n < 4; ++n){
                const int col = c0 + n * 16;
                const f32x4 bd = *(const f32x4*)&bias[col];
                f32x4 v = acc[m][n] + bd;
                __builtin_nontemporal_store(v, (f32x4*)&crow[col]);
            }
        }
    }
}

// ---------------------------------------------------------------------------
// K2: 127 LSTM steps, ONE cooperative kernel (256 blocks x 512 thr):
//   blocks 0..63   : LSTM, 16 units/block, 8-wave K-split. TAGGED h exchange:
//                    each h unit-pair stored as u64 (tag<<32 | 2xbf16) agent
//                    atomic. Consumers POLL THE DATA (tag==t) -- the poll IS
//                    the load: no flags, no drain, raw end-of-step s_barrier.
//                    Depth-2 parity safe: a writer reaches tag t+2 only after
//                    observing tag t+1 on all units => all blocks finished
//                    reading h_t. Parity1 poisoned by init (replay safety).
//   blocks 64..255 : W_out fp32->bf16 under the lstm shadow, then exit.
// ---------------------------------------------------------------------------
__global__ __launch_bounds__(512) void lstm_coop(
    const float*        __restrict__ xg,
    __bf16*             __restrict__ Hall,
    unsigned long long* __restrict__ hbt,   // 2 parities x 16384 tagged u64
    const __bf16*       __restrict__ Whhb,
    const float*        __restrict__ Woutf,
    __bf16*             __restrict__ Woutb)
{
    if (blockIdx.x >= NBLK2){
        if (Woutb){
            const int n4 = VOCAB * HID / 4;          // 8.192M float4
            for (int i = (blockIdx.x - NBLK2) * 512 + threadIdx.x; i < n4; i += 192 * 512){
                float4 v = ((const float4*)Woutf)[i];
                bf16x4 o = { (__bf16)v.x, (__bf16)v.y, (__bf16)v.z, (__bf16)v.w };
                ((bf16x4*)Woutb)[i] = o;
            }
        }
        return;
    }

    __shared__ float lds_g[8 * 8 * 4 * 64];    // [bh*4+cf][wave][q][lane] = 64KB
    const int tid = threadIdx.x, wid = tid >> 6, lane = tid & 63;
    const int jb = blockIdx.x * 16;            // 16 units per block

    // B-frags: 4 col-fragments (= gate types) x 4 ks; this wave's K-eighth.
    bf16x8 bfrag[4][4];
    {
        const int un = lane & 15, ko = (lane >> 4) * 8;
        #pragma unroll
        for (int cf = 0; cf < 4; ++cf){
            const __bf16* base =
                Whhb + ((size_t)cf * HID + jb + un) * HID + wid * 128 + ko;
            #pragma unroll
            for (int ks = 0; ks < 4; ++ks)
                bfrag[cf][ks] = *(const bf16x8*)(base + ks * 32);
        }
    }

    // update-phase ownership: tid<256, (batch b2, 2 units up0..up0+1)
    const int b2 = tid >> 3, up0 = (tid & 7) * 2;
    const int mt2 = b2 >> 4, r2 = b2 & 15, reg2 = r2 & 3, lb2 = (r2 >> 2) << 4;
    float cst[2] = {0.0f, 0.0f};

    const float* xq = xg + (size_t)b2 * G4 + jb + up0;
    float2 xv[4];
    if (tid < 256){
        #pragma unroll
        for (int g = 0; g < 4; ++g) xv[g] = *(const float2*)(xq + g * HID);
    }

    // consumer tagged-word base: batch (lane&15), k-offset wid*128 + (lane>>4)*8
    const size_t i0 = (size_t)(lane & 15) * 512 + wid * 64 + (lane >> 4) * 4;
    const size_t wwr = (size_t)b2 * 512 + jb / 2 + (tid & 7);   // writer word

    for (int t = 0; t < TSTEP; ++t){
        // ---- poll-the-data: 32 tagged u64 loads; retry-all on mismatch ----
        const unsigned long long* tb = hbt + (size_t)(t & 1) * HWORDS;
        const unsigned tagv = (unsigned)t;
        unsigned long long w[2][4][4];
        for (;;){
            #pragma unroll
            for (int bh = 0; bh < 2; ++bh)
                #pragma unroll
                for (int ks = 0; ks < 4; ++ks)
                    #pragma unroll
                    for (int c = 0; c < 4; ++c)
                        w[bh][ks][c] = __hip_atomic_load(
                            tb + i0 + (size_t)bh * (16 * 512) + ks * 16 + c,
                            __ATOMIC_RELAXED, __HIP_MEMORY_SCOPE_AGENT);
            unsigned bad = 0;
            #pragma unroll
            for (int bh = 0; bh < 2; ++bh)
                #pragma unroll
                for (int ks = 0; ks < 4; ++ks)
                    #pragma unroll
                    for (int c = 0; c < 4; ++c)
                        bad |= ((unsigned)(w[bh][ks][c] >> 32)) ^ tagv;
            if (!bad) break;
            __builtin_amdgcn_s_sleep(1);
        }

        // assemble fragments + MFMA
        f32x4 a[2][4] = {};
        #pragma unroll
        for (int ks = 0; ks < 4; ++ks){
            union { unsigned p[4]; bf16x8 v; } f0, f1;
            #pragma unroll
            for (int c = 0; c < 4; ++c){
                f0.p[c] = (unsigned)w[0][ks][c];
                f1.p[c] = (unsigned)w[1][ks][c];
            }
            #pragma unroll
            for (int cf = 0; cf < 4; ++cf){
                a[0][cf] = __builtin_amdgcn_mfma_f32_16x16x32_bf16(f0.v, bfrag[cf][ks], a[0][cf], 0, 0, 0);
                a[1][cf] = __builtin_amdgcn_mfma_f32_16x16x32_bf16(f1.v, bfrag[cf][ks], a[1][cf], 0, 0, 0);
            }
        }
        #pragma unroll
        for (int bh = 0; bh < 2; ++bh)
            #pragma unroll
            for (int cf = 0; cf < 4; ++cf)
                #pragma unroll
                for (int q = 0; q < 4; ++q)
                    lds_g[((((bh * 4 + cf) * 8 + wid) * 4) + q) * 64 + lane] = a[bh][cf][q];
        __syncthreads();

        // ---- update phase: 256 threads, 2 units each ----
        if (tid < 256){
            const float* xn = xq + (size_t)(t + 1) * (BATCH * G4);
            float2 xnew[4];
            #pragma unroll
            for (int g = 0; g < 4; ++g) xnew[g] = *(const float2*)(xn + g * HID);

            float h2[2];
            #pragma unroll
            for (int du = 0; du < 2; ++du){
                int u2 = up0 + du;                 // unit in [0,16)
                float gate[4];
                #pragma unroll
                for (int ty = 0; ty < 4; ++ty){
                    int li = lb2 | u2;
                    float s = 0.0f;
                    #pragma unroll
                    for (int w8 = 0; w8 < 8; ++w8)
                        s += lds_g[((((mt2 * 4 + ty) * 8 + w8) * 4) + reg2) * 64 + li];
                    gate[ty] = s;
                }
                float gi = gate[0] + ((du == 0) ? xv[0].x : xv[0].y);
                float gf = gate[1] + ((du == 0) ? xv[1].x : xv[1].y);
                float gc = gate[2] + ((du == 0) ? xv[2].x : xv[2].y);
                float go = gate[3] + ((du == 0) ? xv[3].x : xv[3].y);
                float c = sigf(gf) * cst[du] + sigf(gi) * tanhfast(gc);
                cst[du] = c;
                h2[du] = sigf(go) * tanhfast(c);
            }
            #pragma unroll
            for (int g = 0; g < 4; ++g) xv[g] = xnew[g];

            union { __bf16 h[2]; unsigned u; } pk;
            pk.h[0] = (__bf16)h2[0]; pk.h[1] = (__bf16)h2[1];
            if (t + 1 < TSTEP){
                // tagged store: data + readiness in ONE message
                unsigned long long wv =
                    ((unsigned long long)(unsigned)(t + 1) << 32) | (unsigned long long)pk.u;
                __hip_atomic_store(hbt + (size_t)((t + 1) & 1) * HWORDS + wwr, wv,
                                   __ATOMIC_RELAXED, __HIP_MEMORY_SCOPE_AGENT);
            }
            *(unsigned*)(Hall + ((size_t)t * BATCH + b2) * HID + jb + up0) = pk.u;
        }

        if (t + 1 == TSTEP) break;
        // raw barrier: protects lds_g (update reads done before this point);
        // tagged stores drain in background -- NOT on the critical path.
        bar();
    }
}

// ---------------------------------------------------------------------------
extern "C" void kernel_launch(void* const* d_in, const int* in_sizes, int n_in,
                              void* d_out, int out_size, void* d_ws, size_t ws_size,
                              hipStream_t stream)
{
    const float* latent = (const float*)d_in[0];
    const int*   tokens = (const int*)d_in[1];
    const float* emb    = (const float*)d_in[2];
    const float* Wlh    = (const float*)d_in[3];
    const float* blh    = (const float*)d_in[4];
    const float* Wih    = (const float*)d_in[5];
    const float* bih    = (const float*)d_in[6];
    const float* Whh    = (const float*)d_in[7];
    const float* bhh    = (const float*)d_in[8];
    const float* Wout   = (const float*)d_in[9];
    const float* bout   = (const float*)d_in[10];
    float* out = (float*)d_out;

    const size_t xg_b   = (size_t)MPAD * G4 * 4;        // 64 MiB fp32 gate preacts
    const size_t hall_b = (size_t)MPAD * HID * 2;       // 8 MiB bf16
    const size_t whh_b  = (size_t)G4 * HID * 2;         // 8 MiB bf16
    const size_t wout_b = (size_t)VOCAB * HID * 2;      // 62.5 MiB bf16
    const size_t hbt_b  = (size_t)2 * HWORDS * 8;       // 256 KiB tagged h ring

    char* p = (char*)d_ws;
    const bool wsA = ws_size >= xg_b + hall_b + whh_b + wout_b + hbt_b;
    const bool wsB = ws_size >= hall_b + whh_b + wout_b + hbt_b;

    float* xg;
    if (wsA){ xg = (float*)p; p += xg_b; }
    else    { xg = (float*)d_out; }      // 64 MiB scratch; consumed before K3 writes
    __bf16* Hall = (__bf16*)p; p += hall_b;
    __bf16* Whhb = (__bf16*)p; p += whh_b;
    __bf16* Woutb = nullptr;
    if (wsA || wsB){ Woutb = (__bf16*)p; p += wout_b; }
    unsigned long long* hbt = (unsigned long long*)p; p += hbt_b;

    init_kernel<<<dim3(192), dim3(256), 0, stream>>>(
        latent, Wlh, blh, hbt, Hall, Whh, Whhb);

    gemm_xg<<<dim3(G4 / 128, MPAD / 128), dim3(256), 0, stream>>>(
        emb, Wih, tokens, xg, bih, bhh);

    {
        const float*        xgc   = xg;
        __bf16*             hallp = Hall;
        unsigned long long* hbp   = hbt;
        const __bf16*       whhp  = Whhb;
        const float*        wof   = Wout;
        __bf16*             wob   = Woutb;
        void* args[] = { (void*)&xgc, (void*)&hallp, (void*)&hbp, (void*)&whhp,
                         (void*)&wof, (void*)&wob };
        (void)hipLaunchCooperativeKernel((void*)lstm_coop, dim3(256), dim3(512),
                                         args, 0, stream);
    }

    if (Woutb)
        gemm_logits<1><<<dim3(NTM * NTN), dim3(256), 0, stream>>>(
            Hall, (const float*)nullptr, Woutb, out, bout);
    else
        gemm_logits<0><<<dim3(NTM * NTN), dim3(256), 0, stream>>>(
            Hall, Wout, (const __bf16*)nullptr, out, bout);
}

// Round 20
// 1188.879 us; speedup vs baseline: 1.4918x; 1.4918x over previous
//
#include <hip/hip_runtime.h>
#include <cstdint>

typedef __bf16 bf16x8 __attribute__((ext_vector_type(8)));
typedef __bf16 bf16x4 __attribute__((ext_vector_type(4)));
typedef float  f32x4  __attribute__((ext_vector_type(4)));

#define VOCAB 32000
#define EMB   512
#define HID   1024
#define LAT   512
#define BATCH 32
#define TSTEP 127          // T-1
#define MROWS 4064         // TSTEP*BATCH
#define MPAD  4096
#define G4    4096         // 4*HID
#define NBLK2 64           // lstm worker blocks (512 thr each)
#define NTM   32           // logits M tiles
#define NTN   250          // logits N tiles
#define FSTRIDE 64         // flag spacing in u32 (256 B apart, line-exclusive)

__device__ __forceinline__ float sigf(float x){ return 1.0f / (1.0f + __expf(-x)); }
__device__ __forceinline__ float tanhfast(float x){
    float ax = fabsf(x);
    float e  = __expf(-2.0f * ax);
    float t  = (1.0f - e) / (1.0f + e);
    return copysignf(t, x);
}

// async global->LDS, 16B/lane; LDS base wave-uniform (HW adds lane*16)
__device__ __forceinline__ void gll16(void* lds, const void* gsrc){
    __builtin_amdgcn_global_load_lds(
        (const __attribute__((address_space(1))) unsigned int*)gsrc,
        (__attribute__((address_space(3))) unsigned int*)lds,
        16, 0, 0);
}

// ---------------------------------------------------------------------------
// K0 (grid 192): blocks 0..127: h0 = latent@W_lh^T + b_lh -> hbuf[0]; zero
// Hall pad rows; zero scattered flags. blocks 128..191: W_hh fp32->bf16.
// ---------------------------------------------------------------------------
__global__ __launch_bounds__(256) void init_kernel(
    const float* __restrict__ latent,
    const float* __restrict__ Wlh,
    const float* __restrict__ blh,
    __bf16* __restrict__ h0,
    __bf16* __restrict__ Hall,
    unsigned* __restrict__ flags,
    const float* __restrict__ Whh,
    __bf16* __restrict__ Whhb)
{
    if (blockIdx.x >= 128){
        const int n4 = G4 * HID / 4;
        for (int i = (blockIdx.x - 128) * 256 + threadIdx.x; i < n4; i += 64 * 256){
            float4 v = ((const float4*)Whh)[i];
            bf16x4 o = { (__bf16)v.x, (__bf16)v.y, (__bf16)v.z, (__bf16)v.w };
            ((bf16x4*)Whhb)[i] = o;
        }
        return;
    }
    if (blockIdx.x == 0 && threadIdx.x < 128)
        flags[threadIdx.x * FSTRIDE] = 0u;     // one flag per 256B line

    int id = blockIdx.x * 256 + threadIdx.x;   // 32768 = BATCH*HID
    int b = id >> 10, j = id & 1023;
    float s = blh[j];
    const float4* lr = (const float4*)(latent + (size_t)b * LAT);
    const float4* wr = (const float4*)(Wlh + (size_t)j * LAT);
    for (int k = 0; k < LAT / 4; ++k){
        float4 a = lr[k], w = wr[k];
        s += a.x * w.x + a.y * w.y + a.z * w.z + a.w * w.w;
    }
    h0[id] = (__bf16)s;                         // hbuf[0][b][j]
    Hall[(size_t)MROWS * HID + id] = (__bf16)0.0f;  // pad rows 4064..4095
}

// ---------------------------------------------------------------------------
// K1: xg[r][4096] = emb[tok(r)] @ W_ih^T + b_ih + b_hh   (fp32 in, fp32 out)
// ---------------------------------------------------------------------------
__global__ __launch_bounds__(256) void gemm_xg(
    const float* __restrict__ emb,
    const float* __restrict__ Wih,
    const int*   __restrict__ tok,
    float*       __restrict__ xg,
    const float* __restrict__ bih,
    const float* __restrict__ bhh)
{
    __shared__ __bf16 As[2][128 * 32];
    __shared__ __bf16 Bs[2][128 * 32];

    const int tid  = threadIdx.x;
    const int wid  = tid >> 6, lane = tid & 63;
    const int tile_n = blockIdx.x, tile_m = blockIdx.y;
    const int wr = wid >> 1, wc = wid & 1;

    f32x4 acc[4][4] = {};

    auto stage = [&](int kt, int buf){
        #pragma unroll
        for (int j = 0; j < 2; ++j){
            const int slot = tid + j * 256;
            const int row  = slot >> 2;
            const int kb   = kt * 32 + (slot & 3) * 8;
            {
                const int brow = tile_n * 128 + row;
                const float4* p = (const float4*)(Wih + (size_t)brow * EMB + kb);
                float4 u = p[0], v = p[1];
                bf16x8 w = { (__bf16)u.x, (__bf16)u.y, (__bf16)u.z, (__bf16)u.w,
                             (__bf16)v.x, (__bf16)v.y, (__bf16)v.z, (__bf16)v.w };
                *(bf16x8*)&Bs[buf][row * 32 + (slot & 3) * 8] = w;
            }
            {
                int r = tile_m * 128 + row;
                int rc = (r < MROWS) ? r : (MROWS - 1);
                int token = tok[(rc & 31) * 128 + (rc >> 5)];   // tokens[b][t]
                const float4* p = (const float4*)(emb + (size_t)token * EMB + kb);
                float4 u = p[0], v = p[1];
                bf16x8 w = { (__bf16)u.x, (__bf16)u.y, (__bf16)u.z, (__bf16)u.w,
                             (__bf16)v.x, (__bf16)v.y, (__bf16)v.z, (__bf16)v.w };
                *(bf16x8*)&As[buf][row * 32 + (slot & 3) * 8] = w;
            }
        }
    };

    const int KT = EMB / 32;
    stage(0, 0);
    for (int kt = 0; kt < KT; ++kt){
        const int buf = kt & 1;
        __syncthreads();
        if (kt + 1 < KT) stage(kt + 1, buf ^ 1);
        const __bf16* Abuf = As[buf];
        const __bf16* Bbuf = Bs[buf];
        const int ar = lane & 15, ko = (lane >> 4) * 8;
        bf16x8 av[4], bv[4];
        #pragma unroll
        for (int m = 0; m < 4; ++m)
            av[m] = *(const bf16x8*)&Abuf[(wr * 64 + m * 16 + ar) * 32 + ko];
        #pragma unroll
        for (int n = 0; n < 4; ++n)
            bv[n] = *(const bf16x8*)&Bbuf[(wc * 64 + n * 16 + ar) * 32 + ko];
        #pragma unroll
        for (int m = 0; m < 4; ++m)
            #pragma unroll
            for (int n = 0; n < 4; ++n)
                acc[m][n] = __builtin_amdgcn_mfma_f32_16x16x32_bf16(av[m], bv[n], acc[m][n], 0, 0, 0);
    }

    const int r0 = tile_m * 128 + wr * 64 + ((lane >> 4) << 2);
    const int c0 = tile_n * 128 + wc * 64 + (lane & 15);
    #pragma unroll
    for (int m = 0; m < 4; ++m){
        #pragma unroll
        for (int n = 0; n < 4; ++n){
            const int col = c0 + n * 16;
            float badd = bih[col] + bhh[col];
            #pragma unroll
            for (int q = 0; q < 4; ++q){
                int row = r0 + m * 16 + q;
                xg[(size_t)row * G4 + col] = acc[m][n][q] + badd;
            }
        }
    }
}

// ---------------------------------------------------------------------------
// K3: logits = Hall @ W_out^T + b_out, 128^2 tile, GROUP_M=8 + XCD swizzle.
// Swapped MFMA operands -> lane holds 4 consecutive output cols -> f32x4
// nontemporal C-stores.
// ---------------------------------------------------------------------------
template<int BF16B>
__global__ __launch_bounds__(256) void gemm_logits(
    const __bf16* __restrict__ A,     // Hall, padded to MPAD rows, K=HID
    const float*  __restrict__ Bf,    // W_out fp32 (BF16B=0)
    const __bf16* __restrict__ Bb,    // W_out bf16 (BF16B=1)
    float*        __restrict__ C,
    const float*  __restrict__ bias)
{
    __shared__ __bf16 As[2][128 * 32];
    __shared__ __bf16 Bs[2][128 * 32];

    const int tid  = threadIdx.x;
    const int wid  = tid >> 6, lane = tid & 63;
    const int bid = blockIdx.x;
    const int s   = (bid & 7) * (NTM * NTN / 8) + (bid >> 3);
    const int g   = s / (8 * NTN), rem = s % (8 * NTN);
    const int tile_m = g * 8 + (rem & 7);
    const int tile_n = rem >> 3;
    const int wr = wid >> 1, wc = wid & 1;

    f32x4 acc[4][4] = {};

    auto stage = [&](int kt, int buf){
        const int kb = kt * 32 + (lane & 3) * 8;
        #pragma unroll
        for (int c2 = 0; c2 < 2; ++c2){
            int rA = tile_m * 128 + c2 * 64 + wid * 16 + (lane >> 2);
            gll16(&As[buf][c2 * 2048 + wid * 512], A + (size_t)rA * HID + kb);
            if constexpr (BF16B){
                int rB = tile_n * 128 + c2 * 64 + wid * 16 + (lane >> 2);
                gll16(&Bs[buf][c2 * 2048 + wid * 512], Bb + (size_t)rB * HID + kb);
            }
        }
        if constexpr (!BF16B){
            #pragma unroll
            for (int j = 0; j < 2; ++j){
                const int slot = tid + j * 256;
                const int row  = slot >> 2;
                const int kb2  = kt * 32 + (slot & 3) * 8;
                const int brow = tile_n * 128 + row;
                const float4* p = (const float4*)(Bf + (size_t)brow * HID + kb2);
                float4 u = p[0], v = p[1];
                bf16x8 w = { (__bf16)u.x, (__bf16)u.y, (__bf16)u.z, (__bf16)u.w,
                             (__bf16)v.x, (__bf16)v.y, (__bf16)v.z, (__bf16)v.w };
                *(bf16x8*)&Bs[buf][row * 32 + (slot & 3) * 8] = w;
            }
        }
    };

    const int KT = HID / 32;
    stage(0, 0);
    for (int kt = 0; kt < KT; ++kt){
        const int buf = kt & 1;
        __syncthreads();                 // drains vmcnt (gll) + lgkmcnt
        if (kt + 1 < KT) stage(kt + 1, buf ^ 1);
        const __bf16* Abuf = As[buf];
        const __bf16* Bbuf = Bs[buf];
        const int ar = lane & 15, ko = (lane >> 4) * 8;
        bf16x8 av[4], bv[4];
        #pragma unroll
        for (int m = 0; m < 4; ++m)
            av[m] = *(const bf16x8*)&Abuf[(wr * 64 + m * 16 + ar) * 32 + ko];
        #pragma unroll
        for (int n = 0; n < 4; ++n)
            bv[n] = *(const bf16x8*)&Bbuf[(wc * 64 + n * 16 + ar) * 32 + ko];
        #pragma unroll
        for (int m = 0; m < 4; ++m)
            #pragma unroll
            for (int n = 0; n < 4; ++n)
                acc[m][n] = __builtin_amdgcn_mfma_f32_16x16x32_bf16(
                    bv[n], av[m], acc[m][n], 0, 0, 0);   // SWAPPED
    }

    const int r0 = tile_m * 128 + wr * 64 + (lane & 15);
    const int c0 = tile_n * 128 + wc * 64 + ((lane >> 4) << 2);
    #pragma unroll
    for (int m = 0; m < 4; ++m){
        const int row = r0 + m * 16;
        if (row < MROWS){
            const int t = row >> 5, b = row & 31;
            float* crow = &C[((size_t)b * TSTEP + t) * VOCAB];
            #pragma unroll
            for (int n = 0; n < 4; ++n){
                const int col = c0 + n * 16;
                const f32x4 bd = *(const f32x4*)&bias[col];
                f32x4 v = acc[m][n] + bd;
                __builtin_nontemporal_store(v, (f32x4*)&crow[col]);
            }
        }
    }
}

// ---------------------------------------------------------------------------
// K2: 127 LSTM steps, ONE cooperative kernel (256 blocks x 512 thr):
//   blocks 0..63   : LSTM, 16 units each, 8-wave K-split. PRODUCER-SUBSET
//                    wait: wave w consumes h-units [128w,128w+128) written
//                    by blocks [8w,8w+8) only -> each wave polls just its 8
//                    producer flags and starts loads/MFMA immediately (no
//                    global barrier poll). Depth-2 hbuf stays safe: a block
//                    flags t+1 only after ALL its waves read h_t, and
//                    entering step t+1 transitively requires all 64 blocks
//                    at flag>=t+1.
//   blocks 64..255 : W_out fp32->bf16 under the lstm shadow, then exit.
// ---------------------------------------------------------------------------
__global__ __launch_bounds__(512) void lstm_coop(
    const float*  __restrict__ xg,
    __bf16*       __restrict__ Hall,
    __bf16*       __restrict__ hbuf,    // 2 * BATCH*HID ping-pong, [0]=h0
    const __bf16* __restrict__ Whhb,
    unsigned*     __restrict__ flags,   // 64 flags, 256B apart
    const float*  __restrict__ Woutf,
    __bf16*       __restrict__ Woutb)
{
    if (blockIdx.x >= NBLK2){
        if (Woutb){
            const int n4 = VOCAB * HID / 4;          // 8.192M float4
            for (int i = (blockIdx.x - NBLK2) * 512 + threadIdx.x; i < n4; i += 192 * 512){
                float4 v = ((const float4*)Woutf)[i];
                bf16x4 o = { (__bf16)v.x, (__bf16)v.y, (__bf16)v.z, (__bf16)v.w };
                ((bf16x4*)Woutb)[i] = o;
            }
        }
        return;
    }

    __shared__ float lds_g[8 * 8 * 4 * 64];    // [bh*4+cf][wave][q][lane] = 64KB
    const int tid = threadIdx.x, wid = tid >> 6, lane = tid & 63;
    const int jb = blockIdx.x * 16;            // 16 units per block

    // B-frags: 4 col-fragments (= gate types) x 4 ks; this wave's K-eighth.
    bf16x8 bfrag[4][4];
    {
        const int un = lane & 15, ko = (lane >> 4) * 8;
        #pragma unroll
        for (int cf = 0; cf < 4; ++cf){
            const __bf16* base =
                Whhb + ((size_t)cf * HID + jb + un) * HID + wid * 128 + ko;
            #pragma unroll
            for (int ks = 0; ks < 4; ++ks)
                bfrag[cf][ks] = *(const bf16x8*)(base + ks * 32);
        }
    }

    // update-phase ownership: tid<256, (batch b2, 2 units up0..up0+1)
    const int b2 = tid >> 3, up0 = (tid & 7) * 2;
    const int mt2 = b2 >> 4, r2 = b2 & 15, reg2 = r2 & 3, lb2 = (r2 >> 2) << 4;
    float cst[2] = {0.0f, 0.0f};

    const float* xq = xg + (size_t)b2 * G4 + jb + up0;
    float2 xv[4];
    if (tid < 256){
        #pragma unroll
        for (int g = 0; g < 4; ++g) xv[g] = *(const float2*)(xq + g * HID);
    }

    const size_t e0 = (size_t)(lane & 15) * HID + wid * 128 + (lane >> 4) * 8; // elems
    const int pflag = (wid * 8 + (lane & 7)) * FSTRIDE;   // this wave's producers

    for (int t = 0; t < TSTEP; ++t){
        // ---- per-wave producer wait: need flag >= t (h_t slice visible) ----
        if (t > 0){
            const unsigned tgt = (unsigned)t;
            for (;;){
                unsigned f = __hip_atomic_load(&flags[pflag],
                                __ATOMIC_RELAXED, __HIP_MEMORY_SCOPE_AGENT);
                if (f >= tgt) break;
                __builtin_amdgcn_s_sleep(1);
            }
        }

        // ---- batched h loads: this wave's K-eighth, both batch halves ----
        const unsigned long long* hq =
            (const unsigned long long*)(hbuf + (size_t)(t & 1) * (BATCH * HID));
        union { unsigned long long q[2]; bf16x8 v; } xa[8];
        #pragma unroll
        for (int ks = 0; ks < 4; ++ks){
            size_t q0 = (e0 + (size_t)ks * 32) >> 2;
            size_t q1 = q0 + ((size_t)16 * HID >> 2);
            xa[ks].q[0]     = __hip_atomic_load(hq + q0,     __ATOMIC_RELAXED, __HIP_MEMORY_SCOPE_AGENT);
            xa[ks].q[1]     = __hip_atomic_load(hq + q0 + 1, __ATOMIC_RELAXED, __HIP_MEMORY_SCOPE_AGENT);
            xa[4 + ks].q[0] = __hip_atomic_load(hq + q1,     __ATOMIC_RELAXED, __HIP_MEMORY_SCOPE_AGENT);
            xa[4 + ks].q[1] = __hip_atomic_load(hq + q1 + 1, __ATOMIC_RELAXED, __HIP_MEMORY_SCOPE_AGENT);
        }
        f32x4 a[2][4] = {};
        #pragma unroll
        for (int ks = 0; ks < 4; ++ks){
            #pragma unroll
            for (int cf = 0; cf < 4; ++cf){
                a[0][cf] = __builtin_amdgcn_mfma_f32_16x16x32_bf16(xa[ks].v,     bfrag[cf][ks], a[0][cf], 0, 0, 0);
                a[1][cf] = __builtin_amdgcn_mfma_f32_16x16x32_bf16(xa[4 + ks].v, bfrag[cf][ks], a[1][cf], 0, 0, 0);
            }
        }
        #pragma unroll
        for (int bh = 0; bh < 2; ++bh)
            #pragma unroll
            for (int cf = 0; cf < 4; ++cf)
                #pragma unroll
                for (int q = 0; q < 4; ++q)
                    lds_g[((((bh * 4 + cf) * 8 + wid) * 4) + q) * 64 + lane] = a[bh][cf][q];
        __syncthreads();

        // ---- update phase: 256 threads, 2 units each ----
        unsigned pku = 0;
        if (tid < 256){
            const float* xn = xq + (size_t)(t + 1) * (BATCH * G4);
            float2 xnew[4];
            #pragma unroll
            for (int g = 0; g < 4; ++g) xnew[g] = *(const float2*)(xn + g * HID);

            float h2[2];
            #pragma unroll
            for (int du = 0; du < 2; ++du){
                int u2 = up0 + du;                 // unit in [0,16)
                float gate[4];
                #pragma unroll
                for (int ty = 0; ty < 4; ++ty){
                    int li = lb2 | u2;
                    float s = 0.0f;
                    #pragma unroll
                    for (int w = 0; w < 8; ++w)
                        s += lds_g[((((mt2 * 4 + ty) * 8 + w) * 4) + reg2) * 64 + li];
                    gate[ty] = s;
                }
                float gi = gate[0] + ((du == 0) ? xv[0].x : xv[0].y);
                float gf = gate[1] + ((du == 0) ? xv[1].x : xv[1].y);
                float gc = gate[2] + ((du == 0) ? xv[2].x : xv[2].y);
                float go = gate[3] + ((du == 0) ? xv[3].x : xv[3].y);
                float c = sigf(gf) * cst[du] + sigf(gi) * tanhfast(gc);
                cst[du] = c;
                h2[du] = sigf(go) * tanhfast(c);
            }
            #pragma unroll
            for (int g = 0; g < 4; ++g) xv[g] = xnew[g];

            union { __bf16 h[2]; unsigned u; } pk;
            pk.h[0] = (__bf16)h2[0]; pk.h[1] = (__bf16)h2[1];
            pku = pk.u;
            // hot-window agent store (the ONLY store on the drain path)
            unsigned* hw = (unsigned*)(hbuf + (size_t)((t + 1) & 1) * (BATCH * HID)
                                       + (size_t)b2 * HID + jb + up0);
            __hip_atomic_store(hw, pku, __ATOMIC_RELAXED, __HIP_MEMORY_SCOPE_AGENT);
        }

        if (t + 1 == TSTEP){
            if (tid < 256)      // last step: Hall store, flushed at kernel end
                *(unsigned*)(Hall + ((size_t)t * BATCH + b2) * HID + jb + up0) = pku;
            break;
        }

        // ---- publish: drain h stores, then single flag store; NO global poll
        __syncthreads();                 // vmcnt(0): hbuf agent stores COMPLETE
        if (tid == 0)
            __hip_atomic_store(&flags[blockIdx.x * FSTRIDE], (unsigned)(t + 1),
                               __ATOMIC_RELAXED, __HIP_MEMORY_SCOPE_AGENT);
        if (tid < 256)                   // Hall store off the critical path
            *(unsigned*)(Hall + ((size_t)t * BATCH + b2) * HID + jb + up0) = pku;
        // next iteration's per-wave producer poll replaces the global barrier;
        // lds_g reuse is safe: writes happen after that poll + loads + MFMA,
        // and all update-phase reads completed before the drain barrier above.
    }
}

// ---------------------------------------------------------------------------
extern "C" void kernel_launch(void* const* d_in, const int* in_sizes, int n_in,
                              void* d_out, int out_size, void* d_ws, size_t ws_size,
                              hipStream_t stream)
{
    const float* latent = (const float*)d_in[0];
    const int*   tokens = (const int*)d_in[1];
    const float* emb    = (const float*)d_in[2];
    const float* Wlh    = (const float*)d_in[3];
    const float* blh    = (const float*)d_in[4];
    const float* Wih    = (const float*)d_in[5];
    const float* bih    = (const float*)d_in[6];
    const float* Whh    = (const float*)d_in[7];
    const float* bhh    = (const float*)d_in[8];
    const float* Wout   = (const float*)d_in[9];
    const float* bout   = (const float*)d_in[10];
    float* out = (float*)d_out;

    const size_t xg_b   = (size_t)MPAD * G4 * 4;        // 64 MiB fp32 gate preacts
    const size_t hall_b = (size_t)MPAD * HID * 2;       // 8 MiB bf16
    const size_t whh_b  = (size_t)G4 * HID * 2;         // 8 MiB bf16
    const size_t wout_b = (size_t)VOCAB * HID * 2;      // 62.5 MiB bf16
    const size_t hb_b   = (size_t)2 * BATCH * HID * 2;  // 128 KiB ping-pong
    const size_t cnt_b  = (size_t)128 * FSTRIDE * 4;    // 32 KiB scattered flags

    char* p = (char*)d_ws;
    const bool wsA = ws_size >= xg_b + hall_b + whh_b + wout_b + hb_b + cnt_b;
    const bool wsB = ws_size >= hall_b + whh_b + wout_b + hb_b + cnt_b;

    float* xg;
    if (wsA){ xg = (float*)p; p += xg_b; }
    else    { xg = (float*)d_out; }      // 64 MiB scratch; consumed before K3 writes
    __bf16* Hall = (__bf16*)p; p += hall_b;
    __bf16* Whhb = (__bf16*)p; p += whh_b;
    __bf16* Woutb = nullptr;
    if (wsA || wsB){ Woutb = (__bf16*)p; p += wout_b; }
    __bf16* hbuf = (__bf16*)p; p += hb_b;
    unsigned* flags = (unsigned*)p; p += cnt_b;

    init_kernel<<<dim3(192), dim3(256), 0, stream>>>(
        latent, Wlh, blh, hbuf, Hall, flags, Whh, Whhb);

    gemm_xg<<<dim3(G4 / 128, MPAD / 128), dim3(256), 0, stream>>>(
        emb, Wih, tokens, xg, bih, bhh);

    {
        const float*  xgc   = xg;
        __bf16*       hallp = Hall;
        __bf16*       hbp   = hbuf;
        const __bf16* whhp  = Whhb;
        unsigned*     flagp = flags;
        const float*  wof   = Wout;
        __bf16*       wob   = Woutb;
        void* args[] = { (void*)&xgc, (void*)&hallp, (void*)&hbp, (void*)&whhp,
                         (void*)&flagp, (void*)&wof, (void*)&wob };
        (void)hipLaunchCooperativeKernel((void*)lstm_coop, dim3(256), dim3(512),
                                         args, 0, stream);
    }

    if (Woutb)
        gemm_logits<1><<<dim3(NTM * NTN), dim3(256), 0, stream>>>(
            Hall, (const float*)nullptr, Woutb, out, bout);
    else
        gemm_logits<0><<<dim3(NTM * NTN), dim3(256), 0, stream>>>(
            Hall, Wout, (const __bf16*)nullptr, out, bout);
}